// Round 2
// baseline (2958.734 us; speedup 1.0000x reference)
//
#include <hip/hip_runtime.h>
#include <cstdint>
#include <cstddef>

#define ND 8000
#define NL 16000
#define NE 60000
#define NM 50000

#define BM 64
#define BN 64
#define BK 16

// ---------------- GEMM: C = A[M,K] @ B[K,N] (+bias[n]) (+emb[nid[m],n]) ----------------
// used only for the input linears
__global__ __launch_bounds__(256) void gemm_kernel(
    const float* __restrict__ A, const float* __restrict__ B,
    const float* __restrict__ bias, const float* __restrict__ emb, const int* __restrict__ nid,
    float* __restrict__ Cm, int M, int N, int K)
{
    __shared__ float As[BK][BM + 4];
    __shared__ float Bs[BK][BN + 4];
    const int tid = threadIdx.x;
    const int tx = tid & 15, ty = tid >> 4;
    const int bm = blockIdx.y * BM, bn = blockIdx.x * BN;
    float acc[4][4] = {};
    for (int k0 = 0; k0 < K; k0 += BK) {
#pragma unroll
        for (int i = 0; i < 4; ++i) {
            int idx = tid + i * 256;
            int ml = idx >> 4, kl = idx & 15;
            int gm = bm + ml, gk = k0 + kl;
            As[kl][ml] = (gm < M && gk < K) ? A[(size_t)gm * K + gk] : 0.f;
        }
#pragma unroll
        for (int i = 0; i < 4; ++i) {
            int idx = tid + i * 256;
            int kl = idx >> 6, nl = idx & 63;
            int gk = k0 + kl, gn = bn + nl;
            Bs[kl][nl] = (gk < K && gn < N) ? B[(size_t)gk * N + gn] : 0.f;
        }
        __syncthreads();
#pragma unroll
        for (int k = 0; k < BK; ++k) {
            float4 av = *(const float4*)&As[k][ty * 4];
            float4 bv = *(const float4*)&Bs[k][tx * 4];
            float a4[4] = {av.x, av.y, av.z, av.w};
            float b4[4] = {bv.x, bv.y, bv.z, bv.w};
#pragma unroll
            for (int i = 0; i < 4; ++i)
#pragma unroll
                for (int j = 0; j < 4; ++j)
                    acc[i][j] += a4[i] * b4[j];
        }
        __syncthreads();
    }
#pragma unroll
    for (int i = 0; i < 4; ++i) {
        int gm = bm + ty * 4 + i;
        if (gm >= M) continue;
        int gn0 = bn + tx * 4;
        float4 v;
        float* vp = &v.x;
#pragma unroll
        for (int j = 0; j < 4; ++j) {
            float x = acc[i][j];
            int gn = gn0 + j;
            if (bias) x += bias[gn];
            if (emb) x += emb[(size_t)nid[gm] * N + gn];
            vp[j] = x;
        }
        if (gn0 + 3 < N) *(float4*)&Cm[(size_t)gm * N + gn0] = v;
    }
}

// ---------------- fold: Wfold[f][k][h] = sum_c W[k, h*C+c] * a[h, c], f in 0..3 ----------------
__global__ void fold_kernel(const float* __restrict__ Ws, const float* __restrict__ Wd,
                            const float* __restrict__ as_, const float* __restrict__ ad_,
                            float* __restrict__ fw, int Ntot, int C)
{
    int gid = blockIdx.x * blockDim.x + threadIdx.x;
    if (gid >= 4 * 128 * 16) return;
    int f = gid / 2048, rem = gid % 2048;
    int k = rem >> 4, h = rem & 15;
    const float* W = (f == 0 || f == 2) ? Ws : Wd;
    const float* a = (f == 0 || f == 2) ? as_ : ad_;
    if (f >= 2) { W += 128 * Ntot; a += 16 * C; }
    float s = 0.f;
    for (int c = 0; c < C; ++c) s += W[(size_t)k * Ntot + h * C + c] * a[h * C + c];
    fw[gid] = s;
}

// ---------------- score: out[n,16] = H[n,128] @ Wf[128,16] ----------------
__global__ __launch_bounds__(256) void score_kernel(
    const float* __restrict__ Hf, const float* __restrict__ Wf, float* __restrict__ out, int n)
{
    __shared__ float hs[16 * 128];
    __shared__ float ws[128 * 16];
    int tid = threadIdx.x;
    int n0 = blockIdx.x * 16;
#pragma unroll
    for (int i = 0; i < 8; ++i) {
        int idx = tid + i * 256;
        int nl = idx >> 7, k = idx & 127;
        int gn = n0 + nl;
        hs[idx] = (gn < n) ? Hf[(size_t)gn * 128 + k] : 0.f;
        ws[idx] = Wf[idx];
    }
    __syncthreads();
    int nl = tid >> 4, h = tid & 15;
    float s = 0.f;
    for (int k = 0; k < 128; ++k) s += hs[nl * 128 + k] * ws[k * 16 + h];
    int gn = n0 + nl;
    if (gn < n) out[gn * 16 + h] = s;
}

// ---------------- CSR build ----------------
__global__ void hist_kernel(const int* __restrict__ esrc, const int* __restrict__ edst,
                            int* __restrict__ degl, int* __restrict__ degd)
{
    int e = blockIdx.x * blockDim.x + threadIdx.x;
    if (e >= NE) return;
    atomicAdd(&degl[edst[e]], 1);
    atomicAdd(&degd[esrc[e]], 1);
}

__global__ __launch_bounds__(1024) void scan_kernel(const int* __restrict__ deg, int* __restrict__ off, int n)
{
    __shared__ int ps[1024];
    int tid = threadIdx.x;
    int chunk = (n + 1023) >> 10;
    int start = tid * chunk, end = min(start + chunk, n);
    int p = 0;
    for (int i = start; i < end; ++i) p += deg[i];
    ps[tid] = p;
    __syncthreads();
    for (int o = 1; o < 1024; o <<= 1) {
        int v = (tid >= o) ? ps[tid - o] : 0;
        __syncthreads();
        ps[tid] += v;
        __syncthreads();
    }
    int run = ps[tid] - p;
    for (int i = start; i < end; ++i) { off[i] = run; run += deg[i]; }
    if (tid == 1023) off[n] = ps[1023];
}

__global__ void scatter_kernel(const int* __restrict__ esrc, const int* __restrict__ edst,
                               const int* __restrict__ offl, const int* __restrict__ offd,
                               int* __restrict__ curl, int* __restrict__ curd,
                               int* __restrict__ csrl, int* __restrict__ csrd)
{
    int e = blockIdx.x * blockDim.x + threadIdx.x;
    if (e >= NE) return;
    int dl = edst[e]; int p = atomicAdd(&curl[dl], 1); csrl[offl[dl] + p] = e;
    int dd = esrc[e]; int q = atomicAdd(&curd[dd], 1); csrd[offd[dd] + q] = e;
}

// ---------------- fused softmax + per-head aggregation of raw src features ----------------
// hagg[d, h, k] = sum_{e: dst(e)=d} alpha[e,h] * h_src[src(e), k]
// block = one dst node, 256 threads: c = tid&127 (feature), hbase = (tid>>7)*8 (8 heads each)
__global__ __launch_bounds__(256) void hagg_kernel(
    const float* __restrict__ hsrc,  // [n_src, 128]
    const float* __restrict__ ss,    // [n_src, 16]
    const float* __restrict__ sd,    // [n_dst, 16]
    const int* __restrict__ off, const int* __restrict__ csr, const int* __restrict__ srcidx,
    float* __restrict__ hagg)        // [n_dst, 16, 128]
{
    __shared__ float m_s[16], s_s[16];
    __shared__ float alpha_s[16][17];
    __shared__ int src_s[16];
    const int d = blockIdx.x;
    const int tid = threadIdx.x;
    const int e0 = off[d], e1 = off[d + 1];

    if (tid < 16) {
        int h = tid;
        float sdv = sd[d * 16 + h];
        float m = -1e30f;
        for (int e = e0; e < e1; ++e) {
            int sn = srcidx[csr[e]];
            float al = ss[sn * 16 + h] + sdv;
            al = al >= 0.f ? al : 0.2f * al;
            m = fmaxf(m, al);
        }
        float s = 0.f;
        for (int e = e0; e < e1; ++e) {
            int sn = srcidx[csr[e]];
            float al = ss[sn * 16 + h] + sdv;
            al = al >= 0.f ? al : 0.2f * al;
            s += expf(al - m);
        }
        m_s[h] = m;
        s_s[h] = s + 1e-16f;
    }
    __syncthreads();

    float acc[8] = {};
    const int c = tid & 127;
    const int hbase = (tid >> 7) * 8;

    for (int ce = e0; ce < e1; ce += 16) {
        int nc = min(16, e1 - ce);
        if (tid < nc * 16) {
            int ei = tid >> 4, h = tid & 15;
            int sn = srcidx[csr[ce + ei]];
            float al = ss[sn * 16 + h] + sd[d * 16 + h];
            al = al >= 0.f ? al : 0.2f * al;
            alpha_s[ei][h] = expf(al - m_s[h]) / s_s[h];
            if (h == 0) src_s[ei] = sn;
        }
        __syncthreads();
        for (int ei = 0; ei < nc; ++ei) {
            float v = hsrc[(size_t)src_s[ei] * 128 + c];
#pragma unroll
            for (int hh = 0; hh < 8; ++hh)
                acc[hh] += alpha_s[ei][hbase + hh] * v;
        }
        __syncthreads();
    }

#pragma unroll
    for (int hh = 0; hh < 8; ++hh)
        hagg[(size_t)d * 2048 + (size_t)(hbase + hh) * 128 + c] = acc[hh];
}

// ---------------- per-head GEMM + bias + relu + head-mean epilogue ----------------
// out[d, c] = (1/16) * sum_h relu( sum_k hagg[d,h,k] * W[k, h*C+c] + bias[h*C+c] )
// C = head width; TN = col tile; RM = rows per thread. TM = (256/(TN/4))*RM = 128.
template <int C, int TN, int RM>
__global__ __launch_bounds__(256) void ph_gemm_kernel(
    const float* __restrict__ hagg,   // [M, 16, 128]
    const float* __restrict__ W,      // [128, 16*C]
    const float* __restrict__ bias,   // [16*C]
    float* __restrict__ out,          // [M, C]
    int M)
{
    const int Ntot = 16 * C;
    const int TX = TN / 4;
    const int TM = (256 / TX) * RM;
    __shared__ float As[16][TM + 4];
    __shared__ float Bs[16][TN + 4];
    const int tid = threadIdx.x;
    const int tx = tid % TX, ty = tid / TX;
    const int bm = blockIdx.y * TM, bn = blockIdx.x * TN;
    float mean[RM][4] = {};

    for (int h = 0; h < 16; ++h) {
        float acc[RM][4] = {};
        for (int k0 = 0; k0 < 128; k0 += 16) {
            // stage A tile: TM rows x 16 k
#pragma unroll
            for (int i = 0; i < TM * 16 / 256; ++i) {
                int idx = tid + i * 256;
                int ml = idx >> 4, kl = idx & 15;
                int gm = bm + ml;
                As[kl][ml] = (gm < M) ? hagg[(size_t)gm * 2048 + h * 128 + k0 + kl] : 0.f;
            }
            // stage B tile: 16 k x TN cols
#pragma unroll
            for (int i = 0; i < TN * 16 / 256; ++i) {
                int idx = tid + i * 256;
                int kl = idx / TN, nl = idx % TN;
                Bs[kl][nl] = W[(size_t)(k0 + kl) * Ntot + h * C + bn + nl];
            }
            __syncthreads();
#pragma unroll
            for (int k = 0; k < 16; ++k) {
                float a[RM];
#pragma unroll
                for (int i = 0; i < RM; ++i) a[i] = As[k][ty * RM + i];
                float4 bv = *(const float4*)&Bs[k][tx * 4];
                float b4[4] = {bv.x, bv.y, bv.z, bv.w};
#pragma unroll
                for (int i = 0; i < RM; ++i)
#pragma unroll
                    for (int j = 0; j < 4; ++j)
                        acc[i][j] += a[i] * b4[j];
            }
            __syncthreads();
        }
        // epilogue for this head: bias + relu + accumulate mean
#pragma unroll
        for (int j = 0; j < 4; ++j) {
            float bv = bias[h * C + bn + tx * 4 + j];
#pragma unroll
            for (int i = 0; i < RM; ++i)
                mean[i][j] += fmaxf(acc[i][j] + bv, 0.f);
        }
    }

#pragma unroll
    for (int i = 0; i < RM; ++i) {
        int gm = bm + ty * RM + i;
        if (gm >= M) continue;
        float4 v;
        v.x = mean[i][0] * (1.f / 16.f);
        v.y = mean[i][1] * (1.f / 16.f);
        v.z = mean[i][2] * (1.f / 16.f);
        v.w = mean[i][3] * (1.f / 16.f);
        *(float4*)&out[(size_t)gm * C + bn + tx * 4] = v;
    }
}

// ---------------- penalty: out[n,32] = h[n,32] * exp(h[n,:] @ pw + pb) ----------------
__global__ void penalty_kernel(const float* __restrict__ h, const float* __restrict__ pw,
                               const float* __restrict__ pb, float* __restrict__ out, int n)
{
    int i = blockIdx.x * blockDim.x + threadIdx.x;
    if (i >= n) return;
    float t = pb[0];
    const float* hp = h + (size_t)i * 32;
#pragma unroll
    for (int c = 0; c < 32; ++c) t += hp[c] * pw[c];
    float f = expf(t);
    float* op = out + (size_t)i * 32;
#pragma unroll
    for (int c = 0; c < 32; ++c) op[c] = hp[c] * f;
}

// ---------------- final MLP on label edges ----------------
__global__ __launch_bounds__(256) void mlp_kernel(
    const float* __restrict__ hd, const float* __restrict__ hl,
    const int* __restrict__ ls, const int* __restrict__ ld,
    const float* __restrict__ w1, const float* __restrict__ b1,
    const float* __restrict__ w2, const float* __restrict__ b2,
    float* __restrict__ out, int M)
{
    __shared__ float w1s[64 * 64];
    __shared__ float b1s[64];
    __shared__ float w2s[64];
    int tid = threadIdx.x;
#pragma unroll
    for (int i = 0; i < 16; ++i) w1s[tid + i * 256] = w1[tid + i * 256];
    if (tid < 64) { b1s[tid] = b1[tid]; w2s[tid] = w2[tid]; }
    __syncthreads();
    int m = blockIdx.x * 256 + tid;
    if (m >= M) return;
    float f[64];
    const float* hp = hd + (size_t)ls[m] * 32;
    const float* lp = hl + (size_t)ld[m] * 32;
#pragma unroll
    for (int c = 0; c < 32; ++c) { f[c] = hp[c]; f[32 + c] = lp[c]; }
    float o = b2[0];
    for (int j = 0; j < 64; ++j) {
        float hj = b1s[j];
#pragma unroll
        for (int k = 0; k < 64; ++k) hj += f[k] * w1s[k * 64 + j];
        hj = fmaxf(hj, 0.f);
        o += hj * w2s[j];
    }
    out[m] = o;
}

extern "C" void kernel_launch(void* const* d_in, const int* in_sizes, int n_in,
                              void* d_out, int out_size, void* d_ws, size_t ws_size,
                              hipStream_t stream)
{
    const float* x_d = (const float*)d_in[0];
    const float* x_l = (const float*)d_in[1];
    const int* node_id_d = (const int*)d_in[2];
    const int* node_id_l = (const int*)d_in[3];
    const int* edge_src = (const int*)d_in[4];
    const int* edge_dst = (const int*)d_in[5];
    const int* label_src = (const int*)d_in[6];
    const int* label_dst = (const int*)d_in[7];
    const float* emb_d = (const float*)d_in[8];
    const float* emb_l = (const float*)d_in[9];
    const float* lin_dw = (const float*)d_in[10];
    const float* lin_db = (const float*)d_in[11];
    const float* lin_lw = (const float*)d_in[12];
    const float* lin_lb = (const float*)d_in[13];
    const float* Ws[3] = {(const float*)d_in[14], (const float*)d_in[19], (const float*)d_in[24]};
    const float* Wd[3] = {(const float*)d_in[15], (const float*)d_in[20], (const float*)d_in[25]};
    const float* as_[3] = {(const float*)d_in[16], (const float*)d_in[21], (const float*)d_in[26]};
    const float* ad_[3] = {(const float*)d_in[17], (const float*)d_in[22], (const float*)d_in[27]};
    const float* bb[3] = {(const float*)d_in[18], (const float*)d_in[23], (const float*)d_in[28]};
    const int NtotL[3] = {2048, 2048, 512};
    const float* pw = (const float*)d_in[29];
    const float* pb = (const float*)d_in[30];
    const float* fc1w = (const float*)d_in[31];
    const float* fc1b = (const float*)d_in[32];
    const float* fc2w = (const float*)d_in[33];
    const float* fc2b = (const float*)d_in[34];

    char* wsb = (char*)d_ws;
    size_t woff = 0;
    auto carve = [&](size_t bytes) -> void* {
        woff = (woff + 255) & ~(size_t)255;
        void* p = wsb + woff;
        woff += bytes;
        return p;
    };
    float* hdA = (float*)carve((size_t)ND * 128 * 4);
    float* hdB = (float*)carve((size_t)ND * 128 * 4);
    float* hlA = (float*)carve((size_t)NL * 128 * 4);
    float* hlB = (float*)carve((size_t)NL * 128 * 4);
    float* hagg = (float*)carve((size_t)NL * 2048 * 4);
    float* ssb = (float*)carve((size_t)NL * 16 * 4);
    float* sdb = (float*)carve((size_t)NL * 16 * 4);
    float* fw  = (float*)carve((size_t)4 * 2048 * 4);
    int* degl = (int*)carve((size_t)NL * 4);
    int* degd = (int*)carve((size_t)ND * 4);
    int* curl = (int*)carve((size_t)NL * 4);
    int* curd = (int*)carve((size_t)ND * 4);
    int* offl = (int*)carve((size_t)(NL + 1) * 4);
    int* offd = (int*)carve((size_t)(ND + 1) * 4);
    int* csrl = (int*)carve((size_t)NE * 4);
    int* csrd = (int*)carve((size_t)NE * 4);
    float* hdp = (float*)carve((size_t)ND * 32 * 4);
    float* hlp = (float*)carve((size_t)NL * 32 * 4);

    hipMemsetAsync(degl, 0, NL * 4, stream);
    hipMemsetAsync(degd, 0, ND * 4, stream);
    hipMemsetAsync(curl, 0, NL * 4, stream);
    hipMemsetAsync(curd, 0, ND * 4, stream);

    hist_kernel<<<(NE + 255) / 256, 256, 0, stream>>>(edge_src, edge_dst, degl, degd);
    scan_kernel<<<1, 1024, 0, stream>>>(degl, offl, NL);
    scan_kernel<<<1, 1024, 0, stream>>>(degd, offd, ND);
    scatter_kernel<<<(NE + 255) / 256, 256, 0, stream>>>(edge_src, edge_dst, offl, offd, curl, curd, csrl, csrd);

    // input linears + embedding add
    gemm_kernel<<<dim3(128 / BN, ND / BM), 256, 0, stream>>>(x_d, lin_dw, lin_db, emb_d, node_id_d, hdA, ND, 128, 412);
    gemm_kernel<<<dim3(128 / BN, NL / BM), 256, 0, stream>>>(x_l, lin_lw, lin_lb, emb_l, node_id_l, hlA, NL, 128, 240);

    float* hd_cur = hdA; float* hd_nxt = hdB;
    float* hl_cur = hlA; float* hl_nxt = hlB;
    for (int L = 0; L < 3; ++L) {
        int Ntot = NtotL[L], C = Ntot / 16;
        fold_kernel<<<(4 * 128 * 16 + 255) / 256, 256, 0, stream>>>(Ws[L], Wd[L], as_[L], ad_[L], fw, Ntot, C);

        // edge type 0: disease -> lncrna (dst = lncrna)
        score_kernel<<<ND / 16, 256, 0, stream>>>(hd_cur, fw + 0 * 2048, ssb, ND);
        score_kernel<<<NL / 16, 256, 0, stream>>>(hl_cur, fw + 1 * 2048, sdb, NL);
        hagg_kernel<<<NL, 256, 0, stream>>>(hd_cur, ssb, sdb, offl, csrl, edge_src, hagg);
        if (C == 128)
            ph_gemm_kernel<128, 64, 8><<<dim3(2, (NL + 127) / 128), 256, 0, stream>>>(hagg, Ws[L], bb[L], hl_nxt, NL);
        else
            ph_gemm_kernel<32, 32, 4><<<dim3(1, (NL + 127) / 128), 256, 0, stream>>>(hagg, Ws[L], bb[L], hl_nxt, NL);

        // edge type 1: lncrna -> disease (dst = disease)
        score_kernel<<<NL / 16, 256, 0, stream>>>(hl_cur, fw + 2 * 2048, ssb, NL);
        score_kernel<<<ND / 16, 256, 0, stream>>>(hd_cur, fw + 3 * 2048, sdb, ND);
        hagg_kernel<<<ND, 256, 0, stream>>>(hl_cur, ssb, sdb, offd, csrd, edge_dst, hagg);
        if (C == 128)
            ph_gemm_kernel<128, 64, 8><<<dim3(2, (ND + 127) / 128), 256, 0, stream>>>(hagg, Ws[L] + 128 * Ntot, bb[L] + Ntot, hd_nxt, ND);
        else
            ph_gemm_kernel<32, 32, 4><<<dim3(1, (ND + 127) / 128), 256, 0, stream>>>(hagg, Ws[L] + 128 * Ntot, bb[L] + Ntot, hd_nxt, ND);

        float* t;
        t = hd_cur; hd_cur = hd_nxt; hd_nxt = t;
        t = hl_cur; hl_cur = hl_nxt; hl_nxt = t;
    }

    penalty_kernel<<<(ND + 255) / 256, 256, 0, stream>>>(hd_cur, pw, pb, hdp, ND);
    penalty_kernel<<<(NL + 255) / 256, 256, 0, stream>>>(hl_cur, pw + 32, pb + 1, hlp, NL);
    mlp_kernel<<<(NM + 255) / 256, 256, 0, stream>>>(hdp, hlp, label_src, label_dst,
                                                     fc1w, fc1b, fc2w, fc2b, (float*)d_out, NM);
}

// Round 3
// 2136.240 us; speedup vs baseline: 1.3850x; 1.3850x over previous
//
#include <hip/hip_runtime.h>
#include <cstdint>
#include <cstddef>

#define ND 8000
#define NL 16000
#define NE 60000
#define NM 50000

#define BM 64
#define BN 64
#define BK 16

// ---------------- GEMM: C = A[M,K] @ B[K,N] (+bias[n]) (+emb[nid[m],n]) ----------------
// used only for the input linears
__global__ __launch_bounds__(256) void gemm_kernel(
    const float* __restrict__ A, const float* __restrict__ B,
    const float* __restrict__ bias, const float* __restrict__ emb, const int* __restrict__ nid,
    float* __restrict__ Cm, int M, int N, int K)
{
    __shared__ float As[BK][BM + 4];
    __shared__ float Bs[BK][BN + 4];
    const int tid = threadIdx.x;
    const int tx = tid & 15, ty = tid >> 4;
    const int bm = blockIdx.y * BM, bn = blockIdx.x * BN;
    float acc[4][4] = {};
    for (int k0 = 0; k0 < K; k0 += BK) {
#pragma unroll
        for (int i = 0; i < 4; ++i) {
            int idx = tid + i * 256;
            int ml = idx >> 4, kl = idx & 15;
            int gm = bm + ml, gk = k0 + kl;
            As[kl][ml] = (gm < M && gk < K) ? A[(size_t)gm * K + gk] : 0.f;
        }
#pragma unroll
        for (int i = 0; i < 4; ++i) {
            int idx = tid + i * 256;
            int kl = idx >> 6, nl = idx & 63;
            int gk = k0 + kl, gn = bn + nl;
            Bs[kl][nl] = (gk < K && gn < N) ? B[(size_t)gk * N + gn] : 0.f;
        }
        __syncthreads();
#pragma unroll
        for (int k = 0; k < BK; ++k) {
            float4 av = *(const float4*)&As[k][ty * 4];
            float4 bv = *(const float4*)&Bs[k][tx * 4];
            float a4[4] = {av.x, av.y, av.z, av.w};
            float b4[4] = {bv.x, bv.y, bv.z, bv.w};
#pragma unroll
            for (int i = 0; i < 4; ++i)
#pragma unroll
                for (int j = 0; j < 4; ++j)
                    acc[i][j] += a4[i] * b4[j];
        }
        __syncthreads();
    }
#pragma unroll
    for (int i = 0; i < 4; ++i) {
        int gm = bm + ty * 4 + i;
        if (gm >= M) continue;
        int gn0 = bn + tx * 4;
        float4 v;
        float* vp = &v.x;
#pragma unroll
        for (int j = 0; j < 4; ++j) {
            float x = acc[i][j];
            int gn = gn0 + j;
            if (bias) x += bias[gn];
            if (emb) x += emb[(size_t)nid[gm] * N + gn];
            vp[j] = x;
        }
        if (gn0 + 3 < N) *(float4*)&Cm[(size_t)gm * N + gn0] = v;
    }
}

// ---------------- fold: fw[f][k][h] = sum_c W[k, h*C+c] * a[h, c], f in 0..3 ----------------
__global__ void fold_kernel(const float* __restrict__ Ws, const float* __restrict__ Wd,
                            const float* __restrict__ as_, const float* __restrict__ ad_,
                            float* __restrict__ fw, int Ntot, int C)
{
    int gid = blockIdx.x * blockDim.x + threadIdx.x;
    if (gid >= 4 * 128 * 16) return;
    int f = gid / 2048, rem = gid % 2048;
    int k = rem >> 4, h = rem & 15;
    const float* W = (f == 0 || f == 2) ? Ws : Wd;
    const float* a = (f == 0 || f == 2) ? as_ : ad_;
    if (f >= 2) { W += 128 * Ntot; a += 16 * C; }
    float s = 0.f;
    for (int c = 0; c < C; ++c) s += W[(size_t)k * Ntot + h * C + c] * a[h * C + c];
    fw[gid] = s;
}

// ---------------- score2: two folded projections of the same H in one pass ----------------
// outA[n,16] = H[n,128] @ WfA[128,16]; outB likewise
__global__ __launch_bounds__(256) void score2_kernel(
    const float* __restrict__ Hf, const float* __restrict__ WfA, const float* __restrict__ WfB,
    float* __restrict__ outA, float* __restrict__ outB, int n)
{
    __shared__ float hs[16 * 128];
    __shared__ float wa[128 * 16];
    __shared__ float wb[128 * 16];
    int tid = threadIdx.x;
    int n0 = blockIdx.x * 16;
#pragma unroll
    for (int i = 0; i < 8; ++i) {
        int idx = tid + i * 256;
        int nl = idx >> 7, k = idx & 127;
        int gn = n0 + nl;
        hs[idx] = (gn < n) ? Hf[(size_t)gn * 128 + k] : 0.f;
        wa[idx] = WfA[idx];
        wb[idx] = WfB[idx];
    }
    __syncthreads();
    int nl = tid >> 4, h = tid & 15;
    float sa = 0.f, sb = 0.f;
    for (int k = 0; k < 128; ++k) {
        float hv = hs[nl * 128 + k];
        sa += hv * wa[k * 16 + h];
        sb += hv * wb[k * 16 + h];
    }
    int gn = n0 + nl;
    if (gn < n) { outA[gn * 16 + h] = sa; outB[gn * 16 + h] = sb; }
}

// ---------------- CSR build ----------------
__global__ void hist_kernel(const int* __restrict__ esrc, const int* __restrict__ edst,
                            int* __restrict__ degl, int* __restrict__ degd)
{
    int e = blockIdx.x * blockDim.x + threadIdx.x;
    if (e >= NE) return;
    atomicAdd(&degl[edst[e]], 1);
    atomicAdd(&degd[esrc[e]], 1);
}

__global__ __launch_bounds__(1024) void scan_kernel(const int* __restrict__ deg, int* __restrict__ off, int n)
{
    __shared__ int ps[1024];
    int tid = threadIdx.x;
    int chunk = (n + 1023) >> 10;
    int start = tid * chunk, end = min(start + chunk, n);
    int p = 0;
    for (int i = start; i < end; ++i) p += deg[i];
    ps[tid] = p;
    __syncthreads();
    for (int o = 1; o < 1024; o <<= 1) {
        int v = (tid >= o) ? ps[tid - o] : 0;
        __syncthreads();
        ps[tid] += v;
        __syncthreads();
    }
    int run = ps[tid] - p;
    for (int i = start; i < end; ++i) { off[i] = run; run += deg[i]; }
    if (tid == 1023) off[n] = ps[1023];
}

__global__ void scatter_kernel(const int* __restrict__ esrc, const int* __restrict__ edst,
                               const int* __restrict__ offl, const int* __restrict__ offd,
                               int* __restrict__ curl, int* __restrict__ curd,
                               int* __restrict__ csrl, int* __restrict__ csrd)
{
    int e = blockIdx.x * blockDim.x + threadIdx.x;
    if (e >= NE) return;
    int dl = edst[e]; int p = atomicAdd(&curl[dl], 1); csrl[offl[dl] + p] = e;
    int dd = esrc[e]; int q = atomicAdd(&curd[dd], 1); csrd[offd[dd] + q] = e;
}

// ---------------- fused softmax + per-head aggregation of raw src features ----------------
// hagg[d, h, k] = sum_{e: dst(e)=d} alpha[e,h] * h_src[src(e), k]
__global__ __launch_bounds__(256) void hagg_kernel(
    const float* __restrict__ hsrc,  // [n_src, 128]
    const float* __restrict__ ss,    // [n_src, 16]
    const float* __restrict__ sd,    // [n_dst, 16]
    const int* __restrict__ off, const int* __restrict__ csr, const int* __restrict__ srcidx,
    float* __restrict__ hagg)        // [n_dst, 16, 128]
{
    __shared__ float m_s[16], s_s[16];
    __shared__ float alpha_s[16][17];
    __shared__ int src_s[16];
    const int d = blockIdx.x;
    const int tid = threadIdx.x;
    const int e0 = off[d], e1 = off[d + 1];

    if (tid < 16) {
        int h = tid;
        float sdv = sd[d * 16 + h];
        float m = -1e30f;
        for (int e = e0; e < e1; ++e) {
            int sn = srcidx[csr[e]];
            float al = ss[sn * 16 + h] + sdv;
            al = al >= 0.f ? al : 0.2f * al;
            m = fmaxf(m, al);
        }
        float s = 0.f;
        for (int e = e0; e < e1; ++e) {
            int sn = srcidx[csr[e]];
            float al = ss[sn * 16 + h] + sdv;
            al = al >= 0.f ? al : 0.2f * al;
            s += expf(al - m);
        }
        m_s[h] = m;
        s_s[h] = s + 1e-16f;
    }
    __syncthreads();

    float acc[8] = {};
    const int c = tid & 127;
    const int hbase = (tid >> 7) * 8;

    for (int ce = e0; ce < e1; ce += 16) {
        int nc = min(16, e1 - ce);
        if (tid < nc * 16) {
            int ei = tid >> 4, h = tid & 15;
            int sn = srcidx[csr[ce + ei]];
            float al = ss[sn * 16 + h] + sd[d * 16 + h];
            al = al >= 0.f ? al : 0.2f * al;
            alpha_s[ei][h] = expf(al - m_s[h]) / s_s[h];
            if (h == 0) src_s[ei] = sn;
        }
        __syncthreads();
        for (int ei = 0; ei < nc; ++ei) {
            float v = hsrc[(size_t)src_s[ei] * 128 + c];
#pragma unroll
            for (int hh = 0; hh < 8; ++hh)
                acc[hh] += alpha_s[ei][hbase + hh] * v;
        }
        __syncthreads();
    }

#pragma unroll
    for (int hh = 0; hh < 8; ++hh)
        hagg[(size_t)d * 2048 + (size_t)(hbase + hh) * 128 + c] = acc[hh];
}

// ---------------- head-grouped per-head GEMM + bias + relu + partial head-mean ----------------
// For head group hg: out[d,c] += (1/16) * sum_{h in group} relu( hagg[d,h,:] @ W[:, h*C+c] + bias[h*C+c] )
// Grid: (C/TN, M/TM, 16/HG). out must be zeroed first; groups combine via atomicAdd.
template <int C, int TN, int RM, int HG>
__global__ __launch_bounds__(256) void phg_kernel(
    const float* __restrict__ hagg,   // [M, 16, 128]
    const float* __restrict__ W,      // [128, 16*C]
    const float* __restrict__ bias,   // [16*C]
    float* __restrict__ out,          // [M, C]
    int M)
{
    const int Ntot = 16 * C;
    const int TX = TN / 4;
    const int TY = 256 / TX;
    const int TM = TY * RM;
    __shared__ float As[16][TM + 4];
    __shared__ float Bs[16][TN + 4];
    const int tid = threadIdx.x;
    const int tx = tid % TX, ty = tid / TX;
    const int bm = blockIdx.y * TM, bn = blockIdx.x * TN;
    const int h0 = blockIdx.z * HG;
    float mean[RM][4] = {};

#pragma unroll
    for (int hg = 0; hg < HG; ++hg) {
        const int h = h0 + hg;
        float acc[RM][4] = {};
        for (int k0 = 0; k0 < 128; k0 += 16) {
#pragma unroll
            for (int i = 0; i < TM * 16 / 256; ++i) {
                int idx = tid + i * 256;
                int ml = idx >> 4, kl = idx & 15;
                int gm = bm + ml;
                As[kl][ml] = (gm < M) ? hagg[(size_t)gm * 2048 + h * 128 + k0 + kl] : 0.f;
            }
#pragma unroll
            for (int i = 0; i < TN * 16 / 256; ++i) {
                int idx = tid + i * 256;
                int kl = idx / TN, nl = idx % TN;
                Bs[kl][nl] = W[(size_t)(k0 + kl) * Ntot + h * C + bn + nl];
            }
            __syncthreads();
#pragma unroll
            for (int k = 0; k < 16; ++k) {
                float a[RM];
#pragma unroll
                for (int i = 0; i < RM; ++i) a[i] = As[k][ty * RM + i];
                float4 bv = *(const float4*)&Bs[k][tx * 4];
                float b4[4] = {bv.x, bv.y, bv.z, bv.w};
#pragma unroll
                for (int i = 0; i < RM; ++i)
#pragma unroll
                    for (int j = 0; j < 4; ++j)
                        acc[i][j] += a[i] * b4[j];
            }
            __syncthreads();
        }
#pragma unroll
        for (int j = 0; j < 4; ++j) {
            float bv = bias[h * C + bn + tx * 4 + j];
#pragma unroll
            for (int i = 0; i < RM; ++i)
                mean[i][j] += fmaxf(acc[i][j] + bv, 0.f);
        }
    }

#pragma unroll
    for (int i = 0; i < RM; ++i) {
        int gm = bm + ty * RM + i;
        if (gm >= M) continue;
#pragma unroll
        for (int j = 0; j < 4; ++j)
            atomicAdd(&out[(size_t)gm * C + bn + tx * 4 + j], mean[i][j] * (1.f / 16.f));
    }
}

// ---------------- penalty: out[n,32] = h[n,32] * exp(h[n,:] @ pw + pb) ----------------
__global__ void penalty_kernel(const float* __restrict__ h, const float* __restrict__ pw,
                               const float* __restrict__ pb, float* __restrict__ out, int n)
{
    int i = blockIdx.x * blockDim.x + threadIdx.x;
    if (i >= n) return;
    float t = pb[0];
    const float* hp = h + (size_t)i * 32;
#pragma unroll
    for (int c = 0; c < 32; ++c) t += hp[c] * pw[c];
    float f = expf(t);
    float* op = out + (size_t)i * 32;
#pragma unroll
    for (int c = 0; c < 32; ++c) op[c] = hp[c] * f;
}

// ---------------- final MLP on label edges ----------------
__global__ __launch_bounds__(256) void mlp_kernel(
    const float* __restrict__ hd, const float* __restrict__ hl,
    const int* __restrict__ ls, const int* __restrict__ ld,
    const float* __restrict__ w1, const float* __restrict__ b1,
    const float* __restrict__ w2, const float* __restrict__ b2,
    float* __restrict__ out, int M)
{
    __shared__ float w1s[64 * 64];
    __shared__ float b1s[64];
    __shared__ float w2s[64];
    int tid = threadIdx.x;
#pragma unroll
    for (int i = 0; i < 16; ++i) w1s[tid + i * 256] = w1[tid + i * 256];
    if (tid < 64) { b1s[tid] = b1[tid]; w2s[tid] = w2[tid]; }
    __syncthreads();
    int m = blockIdx.x * 256 + tid;
    if (m >= M) return;
    float f[64];
    const float* hp = hd + (size_t)ls[m] * 32;
    const float* lp = hl + (size_t)ld[m] * 32;
#pragma unroll
    for (int c = 0; c < 32; ++c) { f[c] = hp[c]; f[32 + c] = lp[c]; }
    float o = b2[0];
    for (int j = 0; j < 64; ++j) {
        float hj = b1s[j];
#pragma unroll
        for (int k = 0; k < 64; ++k) hj += f[k] * w1s[k * 64 + j];
        hj = fmaxf(hj, 0.f);
        o += hj * w2s[j];
    }
    out[m] = o;
}

extern "C" void kernel_launch(void* const* d_in, const int* in_sizes, int n_in,
                              void* d_out, int out_size, void* d_ws, size_t ws_size,
                              hipStream_t stream)
{
    const float* x_d = (const float*)d_in[0];
    const float* x_l = (const float*)d_in[1];
    const int* node_id_d = (const int*)d_in[2];
    const int* node_id_l = (const int*)d_in[3];
    const int* edge_src = (const int*)d_in[4];
    const int* edge_dst = (const int*)d_in[5];
    const int* label_src = (const int*)d_in[6];
    const int* label_dst = (const int*)d_in[7];
    const float* emb_d = (const float*)d_in[8];
    const float* emb_l = (const float*)d_in[9];
    const float* lin_dw = (const float*)d_in[10];
    const float* lin_db = (const float*)d_in[11];
    const float* lin_lw = (const float*)d_in[12];
    const float* lin_lb = (const float*)d_in[13];
    const float* Ws[3] = {(const float*)d_in[14], (const float*)d_in[19], (const float*)d_in[24]};
    const float* Wd[3] = {(const float*)d_in[15], (const float*)d_in[20], (const float*)d_in[25]};
    const float* as_[3] = {(const float*)d_in[16], (const float*)d_in[21], (const float*)d_in[26]};
    const float* ad_[3] = {(const float*)d_in[17], (const float*)d_in[22], (const float*)d_in[27]};
    const float* bb[3] = {(const float*)d_in[18], (const float*)d_in[23], (const float*)d_in[28]};
    const int NtotL[3] = {2048, 2048, 512};
    const float* pw = (const float*)d_in[29];
    const float* pb = (const float*)d_in[30];
    const float* fc1w = (const float*)d_in[31];
    const float* fc1b = (const float*)d_in[32];
    const float* fc2w = (const float*)d_in[33];
    const float* fc2b = (const float*)d_in[34];

    char* wsb = (char*)d_ws;
    size_t woff = 0;
    auto carve = [&](size_t bytes) -> void* {
        woff = (woff + 255) & ~(size_t)255;
        void* p = wsb + woff;
        woff += bytes;
        return p;
    };
    float* hdA = (float*)carve((size_t)ND * 128 * 4);
    float* hdB = (float*)carve((size_t)ND * 128 * 4);
    float* hlA = (float*)carve((size_t)NL * 128 * 4);
    float* hlB = (float*)carve((size_t)NL * 128 * 4);
    float* hagg = (float*)carve((size_t)NL * 2048 * 4);
    float* ssb0 = (float*)carve((size_t)ND * 16 * 4);   // src scores, type 0 (disease src)
    float* sdb0 = (float*)carve((size_t)NL * 16 * 4);   // dst scores, type 0 (lncrna dst)
    float* ssb1 = (float*)carve((size_t)NL * 16 * 4);   // src scores, type 1 (lncrna src)
    float* sdb1 = (float*)carve((size_t)ND * 16 * 4);   // dst scores, type 1 (disease dst)
    float* fw  = (float*)carve((size_t)4 * 2048 * 4);
    int* degl = (int*)carve((size_t)NL * 4);
    int* degd = (int*)carve((size_t)ND * 4);
    int* curl = (int*)carve((size_t)NL * 4);
    int* curd = (int*)carve((size_t)ND * 4);
    int* offl = (int*)carve((size_t)(NL + 1) * 4);
    int* offd = (int*)carve((size_t)(ND + 1) * 4);
    int* csrl = (int*)carve((size_t)NE * 4);
    int* csrd = (int*)carve((size_t)NE * 4);
    float* hdp = (float*)carve((size_t)ND * 32 * 4);
    float* hlp = (float*)carve((size_t)NL * 32 * 4);

    hipMemsetAsync(degl, 0, NL * 4, stream);
    hipMemsetAsync(degd, 0, ND * 4, stream);
    hipMemsetAsync(curl, 0, NL * 4, stream);
    hipMemsetAsync(curd, 0, ND * 4, stream);

    hist_kernel<<<(NE + 255) / 256, 256, 0, stream>>>(edge_src, edge_dst, degl, degd);
    scan_kernel<<<1, 1024, 0, stream>>>(degl, offl, NL);
    scan_kernel<<<1, 1024, 0, stream>>>(degd, offd, ND);
    scatter_kernel<<<(NE + 255) / 256, 256, 0, stream>>>(edge_src, edge_dst, offl, offd, curl, curd, csrl, csrd);

    // input linears + embedding add
    gemm_kernel<<<dim3(128 / BN, ND / BM), 256, 0, stream>>>(x_d, lin_dw, lin_db, emb_d, node_id_d, hdA, ND, 128, 412);
    gemm_kernel<<<dim3(128 / BN, NL / BM), 256, 0, stream>>>(x_l, lin_lw, lin_lb, emb_l, node_id_l, hlA, NL, 128, 240);

    float* hd_cur = hdA; float* hd_nxt = hdB;
    float* hl_cur = hlA; float* hl_nxt = hlB;
    for (int L = 0; L < 3; ++L) {
        int Ntot = NtotL[L], C = Ntot / 16;
        fold_kernel<<<(4 * 128 * 16 + 255) / 256, 256, 0, stream>>>(Ws[L], Wd[L], as_[L], ad_[L], fw, Ntot, C);

        // scores: hd needs fold0 (src of type0) + fold3 (dst of type1); hl needs fold1 (dst of type0) + fold2 (src of type1)
        score2_kernel<<<ND / 16, 256, 0, stream>>>(hd_cur, fw + 0 * 2048, fw + 3 * 2048, ssb0, sdb1, ND);
        score2_kernel<<<NL / 16, 256, 0, stream>>>(hl_cur, fw + 1 * 2048, fw + 2 * 2048, sdb0, ssb1, NL);

        hipMemsetAsync(hl_nxt, 0, (size_t)NL * C * 4, stream);
        hipMemsetAsync(hd_nxt, 0, (size_t)ND * C * 4, stream);

        // edge type 0: disease -> lncrna (dst = lncrna)
        hagg_kernel<<<NL, 256, 0, stream>>>(hd_cur, ssb0, sdb0, offl, csrl, edge_src, hagg);
        if (C == 128)
            phg_kernel<128, 128, 8, 4><<<dim3(1, NL / 64, 4), 256, 0, stream>>>(hagg, Ws[L], bb[L], hl_nxt, NL);
        else
            phg_kernel<32, 32, 2, 2><<<dim3(1, NL / 64, 8), 256, 0, stream>>>(hagg, Ws[L], bb[L], hl_nxt, NL);

        // edge type 1: lncrna -> disease (dst = disease)
        hagg_kernel<<<ND, 256, 0, stream>>>(hl_cur, ssb1, sdb1, offd, csrd, edge_dst, hagg);
        if (C == 128)
            phg_kernel<128, 128, 8, 4><<<dim3(1, ND / 64, 4), 256, 0, stream>>>(hagg, Ws[L] + 128 * Ntot, bb[L] + Ntot, hd_nxt, ND);
        else
            phg_kernel<32, 32, 2, 2><<<dim3(1, ND / 64, 8), 256, 0, stream>>>(hagg, Ws[L] + 128 * Ntot, bb[L] + Ntot, hd_nxt, ND);

        float* t;
        t = hd_cur; hd_cur = hd_nxt; hd_nxt = t;
        t = hl_cur; hl_cur = hl_nxt; hl_nxt = t;
    }

    penalty_kernel<<<(ND + 255) / 256, 256, 0, stream>>>(hd_cur, pw, pb, hdp, ND);
    penalty_kernel<<<(NL + 255) / 256, 256, 0, stream>>>(hl_cur, pw + 32, pb + 1, hlp, NL);
    mlp_kernel<<<(NM + 255) / 256, 256, 0, stream>>>(hdp, hlp, label_src, label_dst,
                                                     fc1w, fc1b, fc2w, fc2b, (float*)d_out, NM);
}

// Round 5
// 1417.464 us; speedup vs baseline: 2.0873x; 1.5071x over previous
//
#include <hip/hip_runtime.h>
#include <cstdint>
#include <cstddef>

#define ND 8000
#define NL 16000
#define NE 60000
#define NM 50000

#define BM 64
#define BN 64
#define BK 16

// ---------------- GEMM: C = A[M,K] @ B[K,N] (+bias[n]) (+emb[nid[m],n]) ----------------
// used only for the input linears
__global__ __launch_bounds__(256) void gemm_kernel(
    const float* __restrict__ A, const float* __restrict__ B,
    const float* __restrict__ bias, const float* __restrict__ emb, const int* __restrict__ nid,
    float* __restrict__ Cm, int M, int N, int K)
{
    __shared__ float As[BK][BM + 4];
    __shared__ float Bs[BK][BN + 4];
    const int tid = threadIdx.x;
    const int tx = tid & 15, ty = tid >> 4;
    const int bm = blockIdx.y * BM, bn = blockIdx.x * BN;
    float acc[4][4] = {};
    for (int k0 = 0; k0 < K; k0 += BK) {
#pragma unroll
        for (int i = 0; i < 4; ++i) {
            int idx = tid + i * 256;
            int ml = idx >> 4, kl = idx & 15;
            int gm = bm + ml, gk = k0 + kl;
            As[kl][ml] = (gm < M && gk < K) ? A[(size_t)gm * K + gk] : 0.f;
        }
#pragma unroll
        for (int i = 0; i < 4; ++i) {
            int idx = tid + i * 256;
            int kl = idx >> 6, nl = idx & 63;
            int gk = k0 + kl, gn = bn + nl;
            Bs[kl][nl] = (gk < K && gn < N) ? B[(size_t)gk * N + gn] : 0.f;
        }
        __syncthreads();
#pragma unroll
        for (int k = 0; k < BK; ++k) {
            float4 av = *(const float4*)&As[k][ty * 4];
            float4 bv = *(const float4*)&Bs[k][tx * 4];
            float a4[4] = {av.x, av.y, av.z, av.w};
            float b4[4] = {bv.x, bv.y, bv.z, bv.w};
#pragma unroll
            for (int i = 0; i < 4; ++i)
#pragma unroll
                for (int j = 0; j < 4; ++j)
                    acc[i][j] += a4[i] * b4[j];
        }
        __syncthreads();
    }
#pragma unroll
    for (int i = 0; i < 4; ++i) {
        int gm = bm + ty * 4 + i;
        if (gm >= M) continue;
        int gn0 = bn + tx * 4;
        float4 v;
        float* vp = &v.x;
#pragma unroll
        for (int j = 0; j < 4; ++j) {
            float x = acc[i][j];
            int gn = gn0 + j;
            if (bias) x += bias[gn];
            if (emb) x += emb[(size_t)nid[gm] * N + gn];
            vp[j] = x;
        }
        if (gn0 + 3 < N) *(float4*)&Cm[(size_t)gm * N + gn0] = v;
    }
}

// ---------------- per-head projection GEMM, IN-PLACE (stage 2) ----------------
// hagg[m, h*128 + c] <- relu( hagg[m, h, :] @ W[:, h*C + c] + bias[h*C + c] ), c < C
// One block owns the FULL head width (TN=C) for an m-tile of one head, so all K reads
// complete (barrier-ordered) before the in-place epilogue stores. Blocks are disjoint
// in (m-tile, head) => race-free. grid: (1, M/TM, 16). K fixed at 128.
// NOTE: A/out intentionally alias; no __restrict__ on them.
template <int C, int RM>
__global__ __launch_bounds__(256) void gemm2_kernel(
    float* hagg,                     // [M, 16*128], in/out
    const float* __restrict__ W,     // [128, 16*C]
    const float* __restrict__ bias,  // [16*C]
    int M)
{
    const int Ntot = 16 * C;
    const int TX = C / 4;            // threads across N
    const int TY = 256 / TX;
    const int TM = TY * RM;          // 64 for both instantiations
    __shared__ float As[16][TM + 4];
    __shared__ float Bs[16][C + 4];
    const int tid = threadIdx.x;
    const int tx = tid % TX, ty = tid / TX;
    const int bm = blockIdx.y * TM;
    const int h = blockIdx.z;
    float acc[RM][4] = {};

    for (int k0 = 0; k0 < 128; k0 += 16) {
#pragma unroll
        for (int i = 0; i < TM * 16 / 256; ++i) {
            int idx = tid + i * 256;
            int ml = idx >> 4, kl = idx & 15;
            int gm = bm + ml;
            As[kl][ml] = (gm < M) ? hagg[(size_t)gm * 2048 + h * 128 + k0 + kl] : 0.f;
        }
#pragma unroll
        for (int i = 0; i < C * 16 / 256; ++i) {
            int idx = tid + i * 256;
            int kl = idx / C, nl = idx % C;
            Bs[kl][nl] = W[(size_t)(k0 + kl) * Ntot + h * C + nl];
        }
        __syncthreads();
#pragma unroll
        for (int k = 0; k < 16; ++k) {
            float a[RM];
#pragma unroll
            for (int i = 0; i < RM; ++i) a[i] = As[k][ty * RM + i];
            float4 bv = *(const float4*)&Bs[k][tx * 4];
            float b4[4] = {bv.x, bv.y, bv.z, bv.w};
#pragma unroll
            for (int i = 0; i < RM; ++i)
#pragma unroll
                for (int j = 0; j < 4; ++j)
                    acc[i][j] += a[i] * b4[j];
        }
        __syncthreads();
    }

#pragma unroll
    for (int i = 0; i < RM; ++i) {
        int gm = bm + ty * RM + i;
        if (gm >= M) continue;
        float4 v;
        float* vp = &v.x;
#pragma unroll
        for (int j = 0; j < 4; ++j)
            vp[j] = fmaxf(acc[i][j] + bias[h * C + tx * 4 + j], 0.f);
        *(float4*)&hagg[(size_t)gm * 2048 + h * 128 + tx * 4] = v;
    }
}

// ---------------- stage 3: mean over 16 heads (from [m][h*128+c] layout) ----------------
// out[m*C+c] = (1/16) * sum_h z[m*2048 + h*128 + c]
__global__ __launch_bounds__(256) void reduce16_kernel(
    const float* __restrict__ z, float* __restrict__ out, int M, int C4)
{
    int i4 = blockIdx.x * 256 + threadIdx.x;
    if (i4 >= M * C4) return;
    int m = i4 / C4, c4 = i4 % C4;
    const float4* zp = (const float4*)(z + (size_t)m * 2048) + c4;
    float4 s = make_float4(0.f, 0.f, 0.f, 0.f);
#pragma unroll
    for (int h = 0; h < 16; ++h) {
        float4 v = zp[h * 32];
        s.x += v.x; s.y += v.y; s.z += v.z; s.w += v.w;
    }
    s.x *= (1.f / 16.f); s.y *= (1.f / 16.f); s.z *= (1.f / 16.f); s.w *= (1.f / 16.f);
    ((float4*)out)[i4] = s;
}

// ---------------- fold: fw[f][k][h] = sum_c W[k, h*C+c] * a[h, c], f in 0..3 ----------------
__global__ void fold_kernel(const float* __restrict__ Ws, const float* __restrict__ Wd,
                            const float* __restrict__ as_, const float* __restrict__ ad_,
                            float* __restrict__ fw, int Ntot, int C)
{
    int gid = blockIdx.x * blockDim.x + threadIdx.x;
    if (gid >= 4 * 128 * 16) return;
    int f = gid / 2048, rem = gid % 2048;
    int k = rem >> 4, h = rem & 15;
    const float* W = (f == 0 || f == 2) ? Ws : Wd;
    const float* a = (f == 0 || f == 2) ? as_ : ad_;
    if (f >= 2) { W += 128 * Ntot; a += 16 * C; }
    float s = 0.f;
    for (int c = 0; c < C; ++c) s += W[(size_t)k * Ntot + h * C + c] * a[h * C + c];
    fw[gid] = s;
}

// ---------------- score2: two folded projections of the same H in one pass ----------------
__global__ __launch_bounds__(256) void score2_kernel(
    const float* __restrict__ Hf, const float* __restrict__ WfA, const float* __restrict__ WfB,
    float* __restrict__ outA, float* __restrict__ outB, int n)
{
    __shared__ float hs[16 * 128];
    __shared__ float wa[128 * 16];
    __shared__ float wb[128 * 16];
    int tid = threadIdx.x;
    int n0 = blockIdx.x * 16;
#pragma unroll
    for (int i = 0; i < 8; ++i) {
        int idx = tid + i * 256;
        int nl = idx >> 7, k = idx & 127;
        int gn = n0 + nl;
        hs[idx] = (gn < n) ? Hf[(size_t)gn * 128 + k] : 0.f;
        wa[idx] = WfA[idx];
        wb[idx] = WfB[idx];
    }
    __syncthreads();
    int nl = tid >> 4, h = tid & 15;
    float sa = 0.f, sb = 0.f;
    for (int k = 0; k < 128; ++k) {
        float hv = hs[nl * 128 + k];
        sa += hv * wa[k * 16 + h];
        sb += hv * wb[k * 16 + h];
    }
    int gn = n0 + nl;
    if (gn < n) { outA[gn * 16 + h] = sa; outB[gn * 16 + h] = sb; }
}

// ---------------- CSR build ----------------
__global__ void hist_kernel(const int* __restrict__ esrc, const int* __restrict__ edst,
                            int* __restrict__ degl, int* __restrict__ degd)
{
    int e = blockIdx.x * blockDim.x + threadIdx.x;
    if (e >= NE) return;
    atomicAdd(&degl[edst[e]], 1);
    atomicAdd(&degd[esrc[e]], 1);
}

__global__ __launch_bounds__(1024) void scan_kernel(const int* __restrict__ deg, int* __restrict__ off, int n)
{
    __shared__ int ps[1024];
    int tid = threadIdx.x;
    int chunk = (n + 1023) >> 10;
    int start = tid * chunk, end = min(start + chunk, n);
    int p = 0;
    for (int i = start; i < end; ++i) p += deg[i];
    ps[tid] = p;
    __syncthreads();
    for (int o = 1; o < 1024; o <<= 1) {
        int v = (tid >= o) ? ps[tid - o] : 0;
        __syncthreads();
        ps[tid] += v;
        __syncthreads();
    }
    int run = ps[tid] - p;
    for (int i = start; i < end; ++i) { off[i] = run; run += deg[i]; }
    if (tid == 1023) off[n] = ps[1023];
}

__global__ void scatter_kernel(const int* __restrict__ esrc, const int* __restrict__ edst,
                               const int* __restrict__ offl, const int* __restrict__ offd,
                               int* __restrict__ curl, int* __restrict__ curd,
                               int* __restrict__ csrl, int* __restrict__ csrd)
{
    int e = blockIdx.x * blockDim.x + threadIdx.x;
    if (e >= NE) return;
    int dl = edst[e]; int p = atomicAdd(&curl[dl], 1); csrl[offl[dl] + p] = e;
    int dd = esrc[e]; int q = atomicAdd(&curd[dd], 1); csrd[offd[dd] + q] = e;
}

// ---------------- fused softmax + per-head aggregation of raw src features ----------------
// hagg[d, h, k] = sum_{e: dst(e)=d} alpha[e,h] * h_src[src(e), k]
__global__ __launch_bounds__(256) void hagg_kernel(
    const float* __restrict__ hsrc,  // [n_src, 128]
    const float* __restrict__ ss,    // [n_src, 16]
    const float* __restrict__ sd,    // [n_dst, 16]
    const int* __restrict__ off, const int* __restrict__ csr, const int* __restrict__ srcidx,
    float* __restrict__ hagg)        // [n_dst, 16, 128]
{
    __shared__ float m_s[16], s_s[16];
    __shared__ float alpha_s[16][17];
    __shared__ int src_s[16];
    const int d = blockIdx.x;
    const int tid = threadIdx.x;
    const int e0 = off[d], e1 = off[d + 1];

    if (tid < 16) {
        int h = tid;
        float sdv = sd[d * 16 + h];
        float m = -1e30f;
        for (int e = e0; e < e1; ++e) {
            int sn = srcidx[csr[e]];
            float al = ss[sn * 16 + h] + sdv;
            al = al >= 0.f ? al : 0.2f * al;
            m = fmaxf(m, al);
        }
        float s = 0.f;
        for (int e = e0; e < e1; ++e) {
            int sn = srcidx[csr[e]];
            float al = ss[sn * 16 + h] + sdv;
            al = al >= 0.f ? al : 0.2f * al;
            s += expf(al - m);
        }
        m_s[h] = m;
        s_s[h] = s + 1e-16f;
    }
    __syncthreads();

    float acc[8] = {};
    const int c = tid & 127;
    const int hbase = (tid >> 7) * 8;

    for (int ce = e0; ce < e1; ce += 16) {
        int nc = min(16, e1 - ce);
        if (tid < nc * 16) {
            int ei = tid >> 4, h = tid & 15;
            int sn = srcidx[csr[ce + ei]];
            float al = ss[sn * 16 + h] + sd[d * 16 + h];
            al = al >= 0.f ? al : 0.2f * al;
            alpha_s[ei][h] = expf(al - m_s[h]) / s_s[h];
            if (h == 0) src_s[ei] = sn;
        }
        __syncthreads();
        for (int ei = 0; ei < nc; ++ei) {
            float v = hsrc[(size_t)src_s[ei] * 128 + c];
#pragma unroll
            for (int hh = 0; hh < 8; ++hh)
                acc[hh] += alpha_s[ei][hbase + hh] * v;
        }
        __syncthreads();
    }

#pragma unroll
    for (int hh = 0; hh < 8; ++hh)
        hagg[(size_t)d * 2048 + (size_t)(hbase + hh) * 128 + c] = acc[hh];
}

// ---------------- penalty: out[n,32] = h[n,32] * exp(h[n,:] @ pw + pb) ----------------
__global__ void penalty_kernel(const float* __restrict__ h, const float* __restrict__ pw,
                               const float* __restrict__ pb, float* __restrict__ out, int n)
{
    int i = blockIdx.x * blockDim.x + threadIdx.x;
    if (i >= n) return;
    float t = pb[0];
    const float* hp = h + (size_t)i * 32;
#pragma unroll
    for (int c = 0; c < 32; ++c) t += hp[c] * pw[c];
    float f = expf(t);
    float* op = out + (size_t)i * 32;
#pragma unroll
    for (int c = 0; c < 32; ++c) op[c] = hp[c] * f;
}

// ---------------- final MLP on label edges ----------------
__global__ __launch_bounds__(256) void mlp_kernel(
    const float* __restrict__ hd, const float* __restrict__ hl,
    const int* __restrict__ ls, const int* __restrict__ ld,
    const float* __restrict__ w1, const float* __restrict__ b1,
    const float* __restrict__ w2, const float* __restrict__ b2,
    float* __restrict__ out, int M)
{
    __shared__ float w1s[64 * 64];
    __shared__ float b1s[64];
    __shared__ float w2s[64];
    int tid = threadIdx.x;
#pragma unroll
    for (int i = 0; i < 16; ++i) w1s[tid + i * 256] = w1[tid + i * 256];
    if (tid < 64) { b1s[tid] = b1[tid]; w2s[tid] = w2[tid]; }
    __syncthreads();
    int m = blockIdx.x * 256 + tid;
    if (m >= M) return;
    float f[64];
    const float* hp = hd + (size_t)ls[m] * 32;
    const float* lp = hl + (size_t)ld[m] * 32;
#pragma unroll
    for (int c = 0; c < 32; ++c) { f[c] = hp[c]; f[32 + c] = lp[c]; }
    float o = b2[0];
    for (int j = 0; j < 64; ++j) {
        float hj = b1s[j];
#pragma unroll
        for (int k = 0; k < 64; ++k) hj += f[k] * w1s[k * 64 + j];
        hj = fmaxf(hj, 0.f);
        o += hj * w2s[j];
    }
    out[m] = o;
}

extern "C" void kernel_launch(void* const* d_in, const int* in_sizes, int n_in,
                              void* d_out, int out_size, void* d_ws, size_t ws_size,
                              hipStream_t stream)
{
    const float* x_d = (const float*)d_in[0];
    const float* x_l = (const float*)d_in[1];
    const int* node_id_d = (const int*)d_in[2];
    const int* node_id_l = (const int*)d_in[3];
    const int* edge_src = (const int*)d_in[4];
    const int* edge_dst = (const int*)d_in[5];
    const int* label_src = (const int*)d_in[6];
    const int* label_dst = (const int*)d_in[7];
    const float* emb_d = (const float*)d_in[8];
    const float* emb_l = (const float*)d_in[9];
    const float* lin_dw = (const float*)d_in[10];
    const float* lin_db = (const float*)d_in[11];
    const float* lin_lw = (const float*)d_in[12];
    const float* lin_lb = (const float*)d_in[13];
    const float* Ws[3] = {(const float*)d_in[14], (const float*)d_in[19], (const float*)d_in[24]};
    const float* Wd[3] = {(const float*)d_in[15], (const float*)d_in[20], (const float*)d_in[25]};
    const float* as_[3] = {(const float*)d_in[16], (const float*)d_in[21], (const float*)d_in[26]};
    const float* ad_[3] = {(const float*)d_in[17], (const float*)d_in[22], (const float*)d_in[27]};
    const float* bb[3] = {(const float*)d_in[18], (const float*)d_in[23], (const float*)d_in[28]};
    const int NtotL[3] = {2048, 2048, 512};
    const float* pw = (const float*)d_in[29];
    const float* pb = (const float*)d_in[30];
    const float* fc1w = (const float*)d_in[31];
    const float* fc1b = (const float*)d_in[32];
    const float* fc2w = (const float*)d_in[33];
    const float* fc2b = (const float*)d_in[34];

    char* wsb = (char*)d_ws;
    size_t woff = 0;
    auto carve = [&](size_t bytes) -> void* {
        woff = (woff + 255) & ~(size_t)255;
        void* p = wsb + woff;
        woff += bytes;
        return p;
    };
    float* hdA = (float*)carve((size_t)ND * 128 * 4);
    float* hdB = (float*)carve((size_t)ND * 128 * 4);
    float* hlA = (float*)carve((size_t)NL * 128 * 4);
    float* hlB = (float*)carve((size_t)NL * 128 * 4);
    float* hagg = (float*)carve((size_t)NL * 2048 * 4);
    float* ssb0 = (float*)carve((size_t)ND * 16 * 4);
    float* sdb0 = (float*)carve((size_t)NL * 16 * 4);
    float* ssb1 = (float*)carve((size_t)NL * 16 * 4);
    float* sdb1 = (float*)carve((size_t)ND * 16 * 4);
    float* fw  = (float*)carve((size_t)4 * 2048 * 4);
    int* degl = (int*)carve((size_t)NL * 4);
    int* degd = (int*)carve((size_t)ND * 4);
    int* curl = (int*)carve((size_t)NL * 4);
    int* curd = (int*)carve((size_t)ND * 4);
    int* offl = (int*)carve((size_t)(NL + 1) * 4);
    int* offd = (int*)carve((size_t)(ND + 1) * 4);
    int* csrl = (int*)carve((size_t)NE * 4);
    int* csrd = (int*)carve((size_t)NE * 4);
    float* hdp = (float*)carve((size_t)ND * 32 * 4);
    float* hlp = (float*)carve((size_t)NL * 32 * 4);

    hipMemsetAsync(degl, 0, NL * 4, stream);
    hipMemsetAsync(degd, 0, ND * 4, stream);
    hipMemsetAsync(curl, 0, NL * 4, stream);
    hipMemsetAsync(curd, 0, ND * 4, stream);

    hist_kernel<<<(NE + 255) / 256, 256, 0, stream>>>(edge_src, edge_dst, degl, degd);
    scan_kernel<<<1, 1024, 0, stream>>>(degl, offl, NL);
    scan_kernel<<<1, 1024, 0, stream>>>(degd, offd, ND);
    scatter_kernel<<<(NE + 255) / 256, 256, 0, stream>>>(edge_src, edge_dst, offl, offd, curl, curd, csrl, csrd);

    // input linears + embedding add
    gemm_kernel<<<dim3(128 / BN, ND / BM), 256, 0, stream>>>(x_d, lin_dw, lin_db, emb_d, node_id_d, hdA, ND, 128, 412);
    gemm_kernel<<<dim3(128 / BN, NL / BM), 256, 0, stream>>>(x_l, lin_lw, lin_lb, emb_l, node_id_l, hlA, NL, 128, 240);

    float* hd_cur = hdA; float* hd_nxt = hdB;
    float* hl_cur = hlA; float* hl_nxt = hlB;
    for (int L = 0; L < 3; ++L) {
        int Ntot = NtotL[L], C = Ntot / 16;
        fold_kernel<<<(4 * 128 * 16 + 255) / 256, 256, 0, stream>>>(Ws[L], Wd[L], as_[L], ad_[L], fw, Ntot, C);

        // scores: hd needs fold0 (src of type0) + fold3 (dst of type1); hl needs fold1 (dst of type0) + fold2 (src of type1)
        score2_kernel<<<ND / 16, 256, 0, stream>>>(hd_cur, fw + 0 * 2048, fw + 3 * 2048, ssb0, sdb1, ND);
        score2_kernel<<<NL / 16, 256, 0, stream>>>(hl_cur, fw + 1 * 2048, fw + 2 * 2048, sdb0, ssb1, NL);

        // edge type 0: disease -> lncrna (dst = lncrna)
        hagg_kernel<<<NL, 256, 0, stream>>>(hd_cur, ssb0, sdb0, offl, csrl, edge_src, hagg);
        if (C == 128)
            gemm2_kernel<128, 8><<<dim3(1, NL / 64, 16), 256, 0, stream>>>(hagg, Ws[L], bb[L], NL);
        else
            gemm2_kernel<32, 2><<<dim3(1, NL / 64, 16), 256, 0, stream>>>(hagg, Ws[L], bb[L], NL);
        reduce16_kernel<<<(NL * (C / 4) + 255) / 256, 256, 0, stream>>>(hagg, hl_nxt, NL, C / 4);

        // edge type 1: lncrna -> disease (dst = disease)
        hagg_kernel<<<ND, 256, 0, stream>>>(hl_cur, ssb1, sdb1, offd, csrd, edge_dst, hagg);
        if (C == 128)
            gemm2_kernel<128, 8><<<dim3(1, ND / 64, 16), 256, 0, stream>>>(hagg, Ws[L] + 128 * Ntot, bb[L] + Ntot, ND);
        else
            gemm2_kernel<32, 2><<<dim3(1, ND / 64, 16), 256, 0, stream>>>(hagg, Ws[L] + 128 * Ntot, bb[L] + Ntot, ND);
        reduce16_kernel<<<(ND * (C / 4) + 255) / 256, 256, 0, stream>>>(hagg, hd_nxt, ND, C / 4);

        float* t;
        t = hd_cur; hd_cur = hd_nxt; hd_nxt = t;
        t = hl_cur; hl_cur = hl_nxt; hl_nxt = t;
    }

    penalty_kernel<<<(ND + 255) / 256, 256, 0, stream>>>(hd_cur, pw, pb, hdp, ND);
    penalty_kernel<<<(NL + 255) / 256, 256, 0, stream>>>(hl_cur, pw + 32, pb + 1, hlp, NL);
    mlp_kernel<<<(NM + 255) / 256, 256, 0, stream>>>(hdp, hlp, label_src, label_dst,
                                                     fc1w, fc1b, fc2w, fc2b, (float*)d_out, NM);
}